// Round 5
// baseline (145.321 us; speedup 1.0000x reference)
//
#include <hip/hip_runtime.h>

typedef short bf16x8 __attribute__((ext_vector_type(8)));
typedef float f32x4 __attribute__((ext_vector_type(4)));

#define KDIM 256
#define BT 128
#define SBLK 256  // stage blocks (fixed; psums reduce assumes 256)

__device__ __forceinline__ unsigned short f2bf(float f) {
  unsigned u = __float_as_uint(f);
  unsigned r = (u + 0x7fffu + ((u >> 16) & 1u)) >> 16;  // RNE
  return (unsigned short)r;
}
__device__ __forceinline__ float bf2f(unsigned short b) {
  return __uint_as_float(((unsigned)b) << 16);
}

__device__ __forceinline__ float2 pk_add(float2 a, float2 b) {
  return make_float2(a.x + b.x, a.y + b.y);
}
__device__ __forceinline__ float2 pk_mul(float2 a, float2 b) {
  return make_float2(a.x * b.x, a.y * b.y);
}
__device__ __forceinline__ float2 pk_fma(float2 a, float2 b, float2 c) {
  return make_float2(__builtin_fmaf(a.x, b.x, c.x),
                     __builtin_fmaf(a.y, b.y, c.y));
}

// Kernel 1: fp32 -> bf16 convert, row sq, per-block column partials + sq-sum
// partials. Plain stores, no global atomics.
__global__ __launch_bounds__(256) void mmd_stage(
    const float* __restrict__ src, const float* __restrict__ tgt, int ns,
    unsigned short* __restrict__ Tbf, float* __restrict__ sq,
    float* __restrict__ pscol, float* __restrict__ psums) {
  __shared__ float sp[256];
  __shared__ float rw[4];
  int t = threadIdx.x;
  int lane = t & 63, wave = t >> 6;
  sp[t] = 0.f;
  __syncthreads();
  int sub = t & 31;   // 8-elem group within row
  int rsel = t >> 5;  // row within 8-row group
  float colacc[8];
#pragma unroll
  for (int j = 0; j < 8; ++j) colacc[j] = 0.f;
  float tsq = 0.f;
#pragma unroll
  for (int it = 0; it < 4; ++it) {
    int r = blockIdx.x * 32 + it * 8 + rsel;
    const float* rp = (r < ns) ? (src + (size_t)r * KDIM)
                               : (tgt + (size_t)(r - ns) * KDIM);
    float4 v0 = *(const float4*)(rp + sub * 8);
    float4 v1 = *(const float4*)(rp + sub * 8 + 4);
    float vals[8] = {v0.x, v0.y, v0.z, v0.w, v1.x, v1.y, v1.z, v1.w};
    unsigned pk[4];
    float ssp = 0.f;
#pragma unroll
    for (int j = 0; j < 4; ++j) {
      unsigned short b0 = f2bf(vals[2 * j]);
      unsigned short b1 = f2bf(vals[2 * j + 1]);
      float x0 = bf2f(b0), x1 = bf2f(b1);
      pk[j] = (unsigned)b0 | ((unsigned)b1 << 16);
      ssp += x0 * x0 + x1 * x1;
      colacc[2 * j] += x0;
      colacc[2 * j + 1] += x1;
    }
    *(uint4*)(Tbf + (size_t)r * KDIM + sub * 8) =
        make_uint4(pk[0], pk[1], pk[2], pk[3]);
    tsq += ssp;
    float ss = ssp;
#pragma unroll
    for (int off = 16; off; off >>= 1) ss += __shfl_down(ss, off, 32);
    if (sub == 0) sq[r] = ss;
  }
#pragma unroll
  for (int j = 0; j < 8; ++j) atomicAdd(&sp[sub * 8 + j], colacc[j]);  // LDS only
#pragma unroll
  for (int off = 32; off; off >>= 1) tsq += __shfl_down(tsq, off, 64);
  if (lane == 0) rw[wave] = tsq;
  __syncthreads();
  pscol[(size_t)blockIdx.x * 256 + t] = sp[t];
  if (t == 0) psums[blockIdx.x] = rw[0] + rw[1] + rw[2] + rw[3];
}

// Kernel 2: fold partials -> bandwidth -> exp2 coefficient; zero d_out.
// sum(L2) = 2n*sum(sq) - 2*||colsum||^2.
__global__ __launch_bounds__(256) void mmd_prep2(
    const float* __restrict__ pscol, const float* __restrict__ psums,
    float* __restrict__ coef, float* __restrict__ out, int n) {
  __shared__ float redP[4], redS[4];
  int t = threadIdx.x;
  int lane = t & 63, wave = t >> 6;
  float cs = 0.f;
#pragma unroll 8
  for (int b = 0; b < SBLK; ++b) cs += pscol[(size_t)b * 256 + t];
  float p = cs * cs;
  float s = psums[t];  // SBLK == 256 == blockDim
#pragma unroll
  for (int off = 32; off; off >>= 1) {
    p += __shfl_down(p, off, 64);
    s += __shfl_down(s, off, 64);
  }
  if (lane == 0) { redP[wave] = p; redS[wave] = s; }
  __syncthreads();
  if (t == 0) {
    double ssq = (double)(redP[0] + redP[1] + redP[2] + redP[3]);
    double S = (double)(redS[0] + redS[1] + redS[2] + redS[3]);
    double nn = (double)n;
    double sumL2 = 2.0 * nn * S - 2.0 * ssq;
    double bw = sumL2 / (nn * nn - nn) / 4.0;  // /= KERNEL_MUL**(KERNEL_NUM//2)
    coef[0] = (float)(-1.4426950408889634 / (16.0 * bw));  // exp2 coefficient
    out[0] = 0.f;
  }
}

// Kernel 3: fused Gram-tile + L2 + 5-kernel sum + reduction.
// LDS-FREE K-loop: MFMA fragments loaded straight from global (L2-resident
// Tbf, 4 MB). Zero barriers in the K-loop -> compiler pipelines 64 loads
// against 128 MFMAs per tile with fine-grained vmcnt (no vmcnt(0) drains).
// Lower-triangular 128x128 tiles; off-diagonal tiles weighted x2 (symmetry).
__global__ __launch_bounds__(256) void mmd_main(
    const unsigned short* __restrict__ Tbf, const float* __restrict__ sq,
    const float* __restrict__ coef, float* __restrict__ out, int halfTiles,
    float inv) {
  __shared__ float sqa[BT];
  __shared__ float sqb[BT];
  __shared__ float red[4];

  int id = blockIdx.x;
  int bi = (int)((sqrtf(8.f * (float)id + 1.f) - 1.f) * 0.5f);
  while ((bi + 1) * (bi + 2) / 2 <= id) ++bi;
  while (bi * (bi + 1) / 2 > id) --bi;
  int bj = id - bi * (bi + 1) / 2;
  int rowBase = bi * BT, colBase = bj * BT;

  int t = threadIdx.x;
  int lane = t & 63, wave = t >> 6;

  if (t < 128) sqa[t] = sq[rowBase + t];
  else sqb[t - 128] = sq[colBase + (t - 128)];
  __syncthreads();  // the only barrier before the reduce

  int wrow = (wave >> 1) * 64, wcol = (wave & 1) * 64;
  int frow = lane & 15;  // fragment row within 16x16 tile
  int kq = lane >> 4;    // k-quad: 8 bf16 (16 B) per lane

  // Per-lane fragment base pointers (A rows from bi-block, B rows from
  // bj-block; B-operand of mfma_16x16x32 takes rows of T -> computes T*T^T).
  const unsigned short* aB[4];
  const unsigned short* bB[4];
#pragma unroll
  for (int mt = 0; mt < 4; ++mt)
    aB[mt] = Tbf + (size_t)(rowBase + wrow + mt * 16 + frow) * KDIM + kq * 8;
#pragma unroll
  for (int nt = 0; nt < 4; ++nt)
    bB[nt] = Tbf + (size_t)(colBase + wcol + nt * 16 + frow) * KDIM + kq * 8;

  f32x4 acc[4][4];
#pragma unroll
  for (int a = 0; a < 4; ++a)
#pragma unroll
    for (int b = 0; b < 4; ++b) {
      f32x4 z = {0.f, 0.f, 0.f, 0.f};
      acc[a][b] = z;
    }

#pragma unroll
  for (int ks = 0; ks < 8; ++ks) {  // K = 8 * 32
    bf16x8 af[4], bfv[4];
#pragma unroll
    for (int mt = 0; mt < 4; ++mt)
      af[mt] = *(const bf16x8*)(aB[mt] + ks * 32);
#pragma unroll
    for (int nt = 0; nt < 4; ++nt)
      bfv[nt] = *(const bf16x8*)(bB[nt] + ks * 32);
#pragma unroll
    for (int mt = 0; mt < 4; ++mt)
#pragma unroll
      for (int nt = 0; nt < 4; ++nt)
        acc[mt][nt] = __builtin_amdgcn_mfma_f32_16x16x32_bf16(
            af[mt], bfv[nt], acc[mt][nt], 0, 0, 0);
  }

  // epilogue: C/D layout col=lane&15, row=(lane>>4)*4+reg [m89]
  // e = exp2(c4*L2), kernels sum = e+e^2+e^4+e^8+e^16 (exact power chain).
  float c4 = coef[0];
  float m2c4 = -2.f * c4;
  float2 m2v = make_float2(m2c4, m2c4);
  int ccol = lane & 15;
  int rb = (lane >> 4) * 4;
  float ra[16];
#pragma unroll
  for (int mt = 0; mt < 4; ++mt)
#pragma unroll
    for (int rg = 0; rg < 4; ++rg)
      ra[mt * 4 + rg] = sqa[wrow + mt * 16 + rb + rg] * c4;
  float cbv[4];
#pragma unroll
  for (int nt = 0; nt < 4; ++nt) cbv[nt] = sqb[wcol + nt * 16 + ccol] * c4;

  float2 lsum2 = make_float2(0.f, 0.f);
#pragma unroll
  for (int mt = 0; mt < 4; ++mt) {
#pragma unroll
    for (int nt = 0; nt < 4; ++nt) {
      float cb = cbv[nt];
#pragma unroll
      for (int rp = 0; rp < 4; rp += 2) {
        float2 g = make_float2(acc[mt][nt][rp], acc[mt][nt][rp + 1]);
        float2 sab =
            make_float2(ra[mt * 4 + rp] + cb, ra[mt * 4 + rp + 1] + cb);
        float2 u = pk_fma(g, m2v, sab);
        float2 e = make_float2(__builtin_amdgcn_exp2f(u.x),
                               __builtin_amdgcn_exp2f(u.y));
        float2 e2 = pk_mul(e, e);
        float2 e4 = pk_mul(e2, e2);
        float2 e8 = pk_mul(e4, e4);
        float2 s = pk_add(e, e2);
        s = pk_add(s, e4);
        s = pk_add(s, e8);
        s = pk_fma(e8, e8, s);  // + e^16
        lsum2 = pk_add(lsum2, s);
      }
    }
  }
  float lsum = lsum2.x + lsum2.y;
#pragma unroll
  for (int off = 32; off; off >>= 1) lsum += __shfl_down(lsum, off, 64);
  if (lane == 0) red[wave] = lsum;
  __syncthreads();
  if (t == 0) {
    float w = ((bi < halfTiles) == (bj < halfTiles)) ? 1.f : -1.f;
    float f = (bi == bj) ? 1.f : 2.f;
    atomicAdd(out, w * f * inv * (red[0] + red[1] + red[2] + red[3]));
  }
}

extern "C" void kernel_launch(void* const* d_in, const int* in_sizes, int n_in,
                              void* d_out, int out_size, void* d_ws,
                              size_t ws_size, hipStream_t stream) {
  const float* src = (const float*)d_in[0];
  const float* tgt = (const float*)d_in[1];
  int ns = in_sizes[0] / KDIM;   // 4096
  int ntr = in_sizes[1] / KDIM;  // 4096
  int n = ns + ntr;              // 8192

  char* ws = (char*)d_ws;
  unsigned short* Tbf = (unsigned short*)ws;  // 4 MiB bf16 matrix
  size_t off = (size_t)n * KDIM * sizeof(unsigned short);
  float* sq = (float*)(ws + off);    off += (size_t)n * 4;
  float* pscol = (float*)(ws + off); off += (size_t)SBLK * 256 * 4;
  float* psums = (float*)(ws + off); off += SBLK * 4;
  float* coef = (float*)(ws + off);

  float* out = (float*)d_out;
  int nb = n / BT;                 // 64
  int nTiles = nb * (nb + 1) / 2;  // 2080

  mmd_stage<<<SBLK, 256, 0, stream>>>(src, tgt, ns, Tbf, sq, pscol, psums);
  mmd_prep2<<<1, 256, 0, stream>>>(pscol, psums, coef, out, n);
  mmd_main<<<nTiles, 256, 0, stream>>>(Tbf, sq, coef, out, ns / BT,
                                       1.f / ((float)ns * (float)ns));
}

// Round 6
// 114.093 us; speedup vs baseline: 1.2737x; 1.2737x over previous
//
#include <hip/hip_runtime.h>

typedef short bf16x8 __attribute__((ext_vector_type(8)));
typedef float f32x4 __attribute__((ext_vector_type(4)));

#define KDIM 256
#define BT 128
#define SBLK 256  // stage blocks (fixed; psums reduce assumes 256)

// Packed-fragment layout of the bf16 matrix ("fragment order"):
// row r = g*16 + ri (g = row-group), col c = ks*32 + kq*8 + e.
// offset(shorts) = g*4096 + ks*512 + kq*128 + ri*8 + e
//                = g*4096 + ks*512 + lane*8   with lane = kq*16 + ri.
// => an MFMA A/B fragment load (row=lane&15, kq=lane>>4) is base + lane*16B:
// one fully-coalesced 1 KiB wave burst, no LDS needed.

__device__ __forceinline__ unsigned short f2bf(float f) {
  unsigned u = __float_as_uint(f);
  unsigned r = (u + 0x7fffu + ((u >> 16) & 1u)) >> 16;  // RNE
  return (unsigned short)r;
}
__device__ __forceinline__ float bf2f(unsigned short b) {
  return __uint_as_float(((unsigned)b) << 16);
}

__device__ __forceinline__ float2 pk_add(float2 a, float2 b) {
  return make_float2(a.x + b.x, a.y + b.y);
}
__device__ __forceinline__ float2 pk_mul(float2 a, float2 b) {
  return make_float2(a.x * b.x, a.y * b.y);
}
__device__ __forceinline__ float2 pk_fma(float2 a, float2 b, float2 c) {
  return make_float2(__builtin_fmaf(a.x, b.x, c.x),
                     __builtin_fmaf(a.y, b.y, c.y));
}

// Kernel 1: fp32 -> bf16 convert (packed-fragment order), row sq, per-block
// column partials + sq-sum partials. Plain stores, no global atomics.
__global__ __launch_bounds__(256) void mmd_stage(
    const float* __restrict__ src, const float* __restrict__ tgt, int ns,
    unsigned short* __restrict__ Tp, float* __restrict__ sq,
    float* __restrict__ pscol, float* __restrict__ psums) {
  __shared__ float sp[256];
  __shared__ float rw[4];
  int t = threadIdx.x;
  int lane = t & 63, wave = t >> 6;
  sp[t] = 0.f;
  __syncthreads();
  int sub = t & 31;   // 8-elem group within row: c0 = sub*8
  int rsel = t >> 5;  // row within 8-row group
  int ks = sub >> 2, kq = sub & 3;
  float colacc[8];
#pragma unroll
  for (int j = 0; j < 8; ++j) colacc[j] = 0.f;
  float tsq = 0.f;
#pragma unroll
  for (int it = 0; it < 4; ++it) {
    int r = blockIdx.x * 32 + it * 8 + rsel;
    const float* rp = (r < ns) ? (src + (size_t)r * KDIM)
                               : (tgt + (size_t)(r - ns) * KDIM);
    float4 v0 = *(const float4*)(rp + sub * 8);
    float4 v1 = *(const float4*)(rp + sub * 8 + 4);
    float vals[8] = {v0.x, v0.y, v0.z, v0.w, v1.x, v1.y, v1.z, v1.w};
    unsigned pk[4];
    float ssp = 0.f;
#pragma unroll
    for (int j = 0; j < 4; ++j) {
      unsigned short b0 = f2bf(vals[2 * j]);
      unsigned short b1 = f2bf(vals[2 * j + 1]);
      float x0 = bf2f(b0), x1 = bf2f(b1);
      pk[j] = (unsigned)b0 | ((unsigned)b1 << 16);
      ssp += x0 * x0 + x1 * x1;
      colacc[2 * j] += x0;
      colacc[2 * j + 1] += x1;
    }
    // packed-fragment store: 16 B at g*4096 + ks*512 + kq*128 + ri*8
    size_t poff = (size_t)(r >> 4) * 4096 + ks * 512 + kq * 128 + (r & 15) * 8;
    *(uint4*)(Tp + poff) = make_uint4(pk[0], pk[1], pk[2], pk[3]);
    tsq += ssp;
    float ss = ssp;
#pragma unroll
    for (int off = 16; off; off >>= 1) ss += __shfl_down(ss, off, 32);
    if (sub == 0) sq[r] = ss;
  }
#pragma unroll
  for (int j = 0; j < 8; ++j) atomicAdd(&sp[sub * 8 + j], colacc[j]);  // LDS only
#pragma unroll
  for (int off = 32; off; off >>= 1) tsq += __shfl_down(tsq, off, 64);
  if (lane == 0) rw[wave] = tsq;
  __syncthreads();
  pscol[(size_t)blockIdx.x * 256 + t] = sp[t];
  if (t == 0) psums[blockIdx.x] = rw[0] + rw[1] + rw[2] + rw[3];
}

// Kernel 2: fold partials -> bandwidth -> exp2 coefficient; zero d_out.
// sum(L2) = 2n*sum(sq) - 2*||colsum||^2.
__global__ __launch_bounds__(256) void mmd_prep2(
    const float* __restrict__ pscol, const float* __restrict__ psums,
    float* __restrict__ coef, float* __restrict__ out, int n) {
  __shared__ float redP[4], redS[4];
  int t = threadIdx.x;
  int lane = t & 63, wave = t >> 6;
  float cs = 0.f;
#pragma unroll 8
  for (int b = 0; b < SBLK; ++b) cs += pscol[(size_t)b * 256 + t];
  float p = cs * cs;
  float s = psums[t];  // SBLK == 256 == blockDim
#pragma unroll
  for (int off = 32; off; off >>= 1) {
    p += __shfl_down(p, off, 64);
    s += __shfl_down(s, off, 64);
  }
  if (lane == 0) { redP[wave] = p; redS[wave] = s; }
  __syncthreads();
  if (t == 0) {
    double ssq = (double)(redP[0] + redP[1] + redP[2] + redP[3]);
    double S = (double)(redS[0] + redS[1] + redS[2] + redS[3]);
    double nn = (double)n;
    double sumL2 = 2.0 * nn * S - 2.0 * ssq;
    double bw = sumL2 / (nn * nn - nn) / 4.0;  // /= KERNEL_MUL**(KERNEL_NUM//2)
    coef[0] = (float)(-1.4426950408889634 / (16.0 * bw));  // exp2 coefficient
    out[0] = 0.f;
  }
}

// Kernel 3: fused Gram-tile + L2 + 5-kernel sum + reduction.
// Barrier-free K-loop, fragments loaded straight from the packed L2-resident
// matrix with perfectly-coalesced base+lane*16B bursts (R5's 16-txn scatter
// was the killer; this is 1 txn-burst per load).
__global__ __launch_bounds__(256) void mmd_main(
    const unsigned short* __restrict__ Tp, const float* __restrict__ sq,
    const float* __restrict__ coef, float* __restrict__ out, int halfTiles,
    float inv) {
  __shared__ float sqa[BT];
  __shared__ float sqb[BT];
  __shared__ float red[4];

  int id = blockIdx.x;
  int bi = (int)((sqrtf(8.f * (float)id + 1.f) - 1.f) * 0.5f);
  while ((bi + 1) * (bi + 2) / 2 <= id) ++bi;
  while (bi * (bi + 1) / 2 > id) --bi;
  int bj = id - bi * (bi + 1) / 2;
  int rowBase = bi * BT, colBase = bj * BT;

  int t = threadIdx.x;
  int lane = t & 63, wave = t >> 6;

  if (t < 128) sqa[t] = sq[rowBase + t];
  else sqb[t - 128] = sq[colBase + (t - 128)];
  __syncthreads();  // only barrier before the reduce

  int wrow = (wave >> 1) * 64, wcol = (wave & 1) * 64;

  // fragment-group base pointers: group g holds 16 rows; fragment (g, ks) is
  // 1 KiB at Tp + g*4096 + ks*512, lane offset lane*8 shorts.
  const unsigned short* aB[4];
  const unsigned short* bB[4];
#pragma unroll
  for (int mt = 0; mt < 4; ++mt)
    aB[mt] = Tp + (size_t)(bi * 8 + (wrow >> 4) + mt) * 4096 + lane * 8;
#pragma unroll
  for (int nt = 0; nt < 4; ++nt)
    bB[nt] = Tp + (size_t)(bj * 8 + (wcol >> 4) + nt) * 4096 + lane * 8;

  f32x4 acc[4][4];
#pragma unroll
  for (int a = 0; a < 4; ++a)
#pragma unroll
    for (int b = 0; b < 4; ++b) {
      f32x4 z = {0.f, 0.f, 0.f, 0.f};
      acc[a][b] = z;
    }

#pragma unroll
  for (int ks = 0; ks < 8; ++ks) {  // K = 8 * 32
    bf16x8 af[4], bfv[4];
#pragma unroll
    for (int mt = 0; mt < 4; ++mt)
      af[mt] = *(const bf16x8*)(aB[mt] + ks * 512);
#pragma unroll
    for (int nt = 0; nt < 4; ++nt)
      bfv[nt] = *(const bf16x8*)(bB[nt] + ks * 512);
#pragma unroll
    for (int mt = 0; mt < 4; ++mt)
#pragma unroll
      for (int nt = 0; nt < 4; ++nt)
        acc[mt][nt] = __builtin_amdgcn_mfma_f32_16x16x32_bf16(
            af[mt], bfv[nt], acc[mt][nt], 0, 0, 0);
  }

  // epilogue: C/D layout col=lane&15, row=(lane>>4)*4+reg [m89]
  // e = exp2(c4*L2), kernels sum = e+e^2+e^4+e^8+e^16 (exact power chain).
  float c4 = coef[0];
  float m2c4 = -2.f * c4;
  float2 m2v = make_float2(m2c4, m2c4);
  int ccol = lane & 15;
  int rb = (lane >> 4) * 4;
  float ra[16];
#pragma unroll
  for (int mt = 0; mt < 4; ++mt)
#pragma unroll
    for (int rg = 0; rg < 4; ++rg)
      ra[mt * 4 + rg] = sqa[wrow + mt * 16 + rb + rg] * c4;
  float cbv[4];
#pragma unroll
  for (int nt = 0; nt < 4; ++nt) cbv[nt] = sqb[wcol + nt * 16 + ccol] * c4;

  float2 lsum2 = make_float2(0.f, 0.f);
#pragma unroll
  for (int mt = 0; mt < 4; ++mt) {
#pragma unroll
    for (int nt = 0; nt < 4; ++nt) {
      float cb = cbv[nt];
#pragma unroll
      for (int rp = 0; rp < 4; rp += 2) {
        float2 g = make_float2(acc[mt][nt][rp], acc[mt][nt][rp + 1]);
        float2 sab =
            make_float2(ra[mt * 4 + rp] + cb, ra[mt * 4 + rp + 1] + cb);
        float2 u = pk_fma(g, m2v, sab);
        float2 e = make_float2(__builtin_amdgcn_exp2f(u.x),
                               __builtin_amdgcn_exp2f(u.y));
        float2 e2 = pk_mul(e, e);
        float2 e4 = pk_mul(e2, e2);
        float2 e8 = pk_mul(e4, e4);
        float2 s = pk_add(e, e2);
        s = pk_add(s, e4);
        s = pk_add(s, e8);
        s = pk_fma(e8, e8, s);  // + e^16
        lsum2 = pk_add(lsum2, s);
      }
    }
  }
  float lsum = lsum2.x + lsum2.y;
#pragma unroll
  for (int off = 32; off; off >>= 1) lsum += __shfl_down(lsum, off, 64);
  if (lane == 0) red[wave] = lsum;
  __syncthreads();
  if (t == 0) {
    float w = ((bi < halfTiles) == (bj < halfTiles)) ? 1.f : -1.f;
    float f = (bi == bj) ? 1.f : 2.f;
    atomicAdd(out, w * f * inv * (red[0] + red[1] + red[2] + red[3]));
  }
}

extern "C" void kernel_launch(void* const* d_in, const int* in_sizes, int n_in,
                              void* d_out, int out_size, void* d_ws,
                              size_t ws_size, hipStream_t stream) {
  const float* src = (const float*)d_in[0];
  const float* tgt = (const float*)d_in[1];
  int ns = in_sizes[0] / KDIM;   // 4096
  int ntr = in_sizes[1] / KDIM;  // 4096
  int n = ns + ntr;              // 8192

  char* ws = (char*)d_ws;
  unsigned short* Tp = (unsigned short*)ws;  // 4 MiB packed bf16 matrix
  size_t off = (size_t)n * KDIM * sizeof(unsigned short);
  float* sq = (float*)(ws + off);    off += (size_t)n * 4;
  float* pscol = (float*)(ws + off); off += (size_t)SBLK * 256 * 4;
  float* psums = (float*)(ws + off); off += SBLK * 4;
  float* coef = (float*)(ws + off);

  float* out = (float*)d_out;
  int nb = n / BT;                 // 64
  int nTiles = nb * (nb + 1) / 2;  // 2080

  mmd_stage<<<SBLK, 256, 0, stream>>>(src, tgt, ns, Tp, sq, pscol, psums);
  mmd_prep2<<<1, 256, 0, stream>>>(pscol, psums, coef, out, n);
  mmd_main<<<nTiles, 256, 0, stream>>>(Tp, sq, coef, out, ns / BT,
                                       1.f / ((float)ns * (float)ns));
}

// Round 7
// 113.156 us; speedup vs baseline: 1.2842x; 1.0083x over previous
//
#include <hip/hip_runtime.h>

typedef short bf16x8 __attribute__((ext_vector_type(8)));
typedef float f32x4 __attribute__((ext_vector_type(4)));

#define KDIM 256
#define BT 128
#define SBLK 256   // stage blocks (fixed; psums reduce assumes 256)
#define PBLK 768   // persistent main blocks (3 per CU target)

// Packed-fragment layout of the bf16 matrix ("fragment order"):
// row r = g*16 + ri (g = row-group), col c = ks*32 + kq*8 + e.
// offset(shorts) = g*4096 + ks*512 + kq*128 + ri*8 + e
//                = g*4096 + ks*512 + lane*8   with lane = kq*16 + ri.
// => an MFMA A/B fragment load (row=lane&15, kq=lane>>4) is base + lane*16B:
// one fully-coalesced 1 KiB wave burst, no LDS needed.

__device__ __forceinline__ unsigned short f2bf(float f) {
  unsigned u = __float_as_uint(f);
  unsigned r = (u + 0x7fffu + ((u >> 16) & 1u)) >> 16;  // RNE
  return (unsigned short)r;
}
__device__ __forceinline__ float bf2f(unsigned short b) {
  return __uint_as_float(((unsigned)b) << 16);
}

__device__ __forceinline__ float2 pk_add(float2 a, float2 b) {
  return make_float2(a.x + b.x, a.y + b.y);
}
__device__ __forceinline__ float2 pk_mul(float2 a, float2 b) {
  return make_float2(a.x * b.x, a.y * b.y);
}
__device__ __forceinline__ float2 pk_fma(float2 a, float2 b, float2 c) {
  return make_float2(__builtin_fmaf(a.x, b.x, c.x),
                     __builtin_fmaf(a.y, b.y, c.y));
}

// Kernel 1: fp32 -> bf16 convert (packed-fragment order), row sq, per-block
// column partials + sq-sum partials. Plain stores, no global atomics.
__global__ __launch_bounds__(256) void mmd_stage(
    const float* __restrict__ src, const float* __restrict__ tgt, int ns,
    unsigned short* __restrict__ Tp, float* __restrict__ sq,
    float* __restrict__ pscol, float* __restrict__ psums) {
  __shared__ float sp[256];
  __shared__ float rw[4];
  int t = threadIdx.x;
  int lane = t & 63, wave = t >> 6;
  sp[t] = 0.f;
  __syncthreads();
  int sub = t & 31;   // 8-elem group within row: c0 = sub*8
  int rsel = t >> 5;  // row within 8-row group
  int ks = sub >> 2, kq = sub & 3;
  float colacc[8];
#pragma unroll
  for (int j = 0; j < 8; ++j) colacc[j] = 0.f;
  float tsq = 0.f;
#pragma unroll
  for (int it = 0; it < 4; ++it) {
    int r = blockIdx.x * 32 + it * 8 + rsel;
    const float* rp = (r < ns) ? (src + (size_t)r * KDIM)
                               : (tgt + (size_t)(r - ns) * KDIM);
    float4 v0 = *(const float4*)(rp + sub * 8);
    float4 v1 = *(const float4*)(rp + sub * 8 + 4);
    float vals[8] = {v0.x, v0.y, v0.z, v0.w, v1.x, v1.y, v1.z, v1.w};
    unsigned pk[4];
    float ssp = 0.f;
#pragma unroll
    for (int j = 0; j < 4; ++j) {
      unsigned short b0 = f2bf(vals[2 * j]);
      unsigned short b1 = f2bf(vals[2 * j + 1]);
      float x0 = bf2f(b0), x1 = bf2f(b1);
      pk[j] = (unsigned)b0 | ((unsigned)b1 << 16);
      ssp += x0 * x0 + x1 * x1;
      colacc[2 * j] += x0;
      colacc[2 * j + 1] += x1;
    }
    // packed-fragment store: 16 B at g*4096 + ks*512 + kq*128 + ri*8
    size_t poff = (size_t)(r >> 4) * 4096 + ks * 512 + kq * 128 + (r & 15) * 8;
    *(uint4*)(Tp + poff) = make_uint4(pk[0], pk[1], pk[2], pk[3]);
    tsq += ssp;
    float ss = ssp;
#pragma unroll
    for (int off = 16; off; off >>= 1) ss += __shfl_down(ss, off, 32);
    if (sub == 0) sq[r] = ss;
  }
#pragma unroll
  for (int j = 0; j < 8; ++j) atomicAdd(&sp[sub * 8 + j], colacc[j]);  // LDS only
#pragma unroll
  for (int off = 32; off; off >>= 1) tsq += __shfl_down(tsq, off, 64);
  if (lane == 0) rw[wave] = tsq;
  __syncthreads();
  pscol[(size_t)blockIdx.x * 256 + t] = sp[t];
  if (t == 0) psums[blockIdx.x] = rw[0] + rw[1] + rw[2] + rw[3];
}

// Kernel 2: fold partials -> bandwidth -> exp2 coefficient; zero d_out.
// sum(L2) = 2n*sum(sq) - 2*||colsum||^2.
__global__ __launch_bounds__(256) void mmd_prep2(
    const float* __restrict__ pscol, const float* __restrict__ psums,
    float* __restrict__ coef, float* __restrict__ out, int n) {
  __shared__ float redP[4], redS[4];
  int t = threadIdx.x;
  int lane = t & 63, wave = t >> 6;
  float cs = 0.f;
#pragma unroll 8
  for (int b = 0; b < SBLK; ++b) cs += pscol[(size_t)b * 256 + t];
  float p = cs * cs;
  float s = psums[t];  // SBLK == 256 == blockDim
#pragma unroll
  for (int off = 32; off; off >>= 1) {
    p += __shfl_down(p, off, 64);
    s += __shfl_down(s, off, 64);
  }
  if (lane == 0) { redP[wave] = p; redS[wave] = s; }
  __syncthreads();
  if (t == 0) {
    double ssq = (double)(redP[0] + redP[1] + redP[2] + redP[3]);
    double S = (double)(redS[0] + redS[1] + redS[2] + redS[3]);
    double nn = (double)n;
    double sumL2 = 2.0 * nn * S - 2.0 * ssq;
    double bw = sumL2 / (nn * nn - nn) / 4.0;  // /= KERNEL_MUL**(KERNEL_NUM//2)
    coef[0] = (float)(-1.4426950408889634 / (16.0 * bw));  // exp2 coefficient
    out[0] = 0.f;
  }
}

// Kernel 3: persistent, fully barrier-free fused Gram + kernel-sum.
// 768 blocks grid-stride over 2080 triangular 128x128 tiles. Fragments come
// straight from the packed L2-resident matrix (coalesced base+lane*16B).
// sq values are read per-lane from global (16+4 distinct floats per wave,
// issued before the K-loop so MFMAs hide them). Per-lane weighted running
// sum across tiles; ONE reduce + ONE atomic per block at kernel end.
__global__ __launch_bounds__(256) void mmd_main(
    const unsigned short* __restrict__ Tp, const float* __restrict__ sq,
    const float* __restrict__ coef, float* __restrict__ out, int halfTiles,
    float inv, int nTiles) {
  __shared__ float red[4];
  int t = threadIdx.x;
  int lane = t & 63, wave = t >> 6;
  int wrow = (wave >> 1) * 64, wcol = (wave & 1) * 64;
  int ccol = lane & 15;
  int rb = (lane >> 4) * 4;

  float c4 = coef[0];
  float m2c4 = -2.f * c4;
  float2 m2v = make_float2(m2c4, m2c4);
  float wsum = 0.f;

  for (int id = blockIdx.x; id < nTiles; id += gridDim.x) {
    int bi = (int)((sqrtf(8.f * (float)id + 1.f) - 1.f) * 0.5f);
    while ((bi + 1) * (bi + 2) / 2 <= id) ++bi;
    while (bi * (bi + 1) / 2 > id) --bi;
    int bj = id - bi * (bi + 1) / 2;

    // sq loads issued up front; consumed only after 128 MFMAs (fully hidden)
    float sra[16];
#pragma unroll
    for (int mt = 0; mt < 4; ++mt)
#pragma unroll
      for (int rg = 0; rg < 4; ++rg)
        sra[mt * 4 + rg] = sq[bi * BT + wrow + mt * 16 + rb + rg];
    float scb[4];
#pragma unroll
    for (int nt = 0; nt < 4; ++nt)
      scb[nt] = sq[bj * BT + wcol + nt * 16 + ccol];

    // fragment-group base pointers: fragment (g, ks) = 1 KiB at
    // Tp + g*4096 + ks*512, lane offset lane*8 shorts.
    const unsigned short* aB[4];
    const unsigned short* bB[4];
#pragma unroll
    for (int mt = 0; mt < 4; ++mt)
      aB[mt] = Tp + (size_t)(bi * 8 + (wrow >> 4) + mt) * 4096 + lane * 8;
#pragma unroll
    for (int nt = 0; nt < 4; ++nt)
      bB[nt] = Tp + (size_t)(bj * 8 + (wcol >> 4) + nt) * 4096 + lane * 8;

    f32x4 acc[4][4];
#pragma unroll
    for (int a = 0; a < 4; ++a)
#pragma unroll
      for (int b = 0; b < 4; ++b) {
        f32x4 z = {0.f, 0.f, 0.f, 0.f};
        acc[a][b] = z;
      }

#pragma unroll
    for (int ks = 0; ks < 8; ++ks) {  // K = 8 * 32
      bf16x8 af[4], bfv[4];
#pragma unroll
      for (int mt = 0; mt < 4; ++mt)
        af[mt] = *(const bf16x8*)(aB[mt] + ks * 512);
#pragma unroll
      for (int nt = 0; nt < 4; ++nt)
        bfv[nt] = *(const bf16x8*)(bB[nt] + ks * 512);
#pragma unroll
      for (int mt = 0; mt < 4; ++mt)
#pragma unroll
        for (int nt = 0; nt < 4; ++nt)
          acc[mt][nt] = __builtin_amdgcn_mfma_f32_16x16x32_bf16(
              af[mt], bfv[nt], acc[mt][nt], 0, 0, 0);
    }

    // epilogue: C/D layout col=lane&15, row=(lane>>4)*4+reg [m89]
    // e = exp2(c4*L2), kernels sum = e+e^2+e^4+e^8+e^16 (exact power chain).
    float2 lsum2 = make_float2(0.f, 0.f);
#pragma unroll
    for (int mt = 0; mt < 4; ++mt) {
#pragma unroll
      for (int nt = 0; nt < 4; ++nt) {
        float cb = scb[nt] * c4;
#pragma unroll
        for (int rp = 0; rp < 4; rp += 2) {
          float2 g = make_float2(acc[mt][nt][rp], acc[mt][nt][rp + 1]);
          float2 sab = make_float2(
              __builtin_fmaf(sra[mt * 4 + rp], c4, cb),
              __builtin_fmaf(sra[mt * 4 + rp + 1], c4, cb));
          float2 u = pk_fma(g, m2v, sab);
          float2 e = make_float2(__builtin_amdgcn_exp2f(u.x),
                                 __builtin_amdgcn_exp2f(u.y));
          float2 e2 = pk_mul(e, e);
          float2 e4 = pk_mul(e2, e2);
          float2 e8 = pk_mul(e4, e4);
          float2 s = pk_add(e, e2);
          s = pk_add(s, e4);
          s = pk_add(s, e8);
          s = pk_fma(e8, e8, s);  // + e^16
          lsum2 = pk_add(lsum2, s);
        }
      }
    }
    float wgt = (((bi < halfTiles) == (bj < halfTiles)) ? 1.f : -1.f) *
                ((bi == bj) ? 1.f : 2.f);
    wsum = __builtin_fmaf(wgt, lsum2.x + lsum2.y, wsum);
  }

  // single end-of-kernel reduction (the only barrier in this kernel)
#pragma unroll
  for (int off = 32; off; off >>= 1) wsum += __shfl_down(wsum, off, 64);
  if (lane == 0) red[wave] = wsum;
  __syncthreads();
  if (t == 0) atomicAdd(out, inv * (red[0] + red[1] + red[2] + red[3]));
}

extern "C" void kernel_launch(void* const* d_in, const int* in_sizes, int n_in,
                              void* d_out, int out_size, void* d_ws,
                              size_t ws_size, hipStream_t stream) {
  const float* src = (const float*)d_in[0];
  const float* tgt = (const float*)d_in[1];
  int ns = in_sizes[0] / KDIM;   // 4096
  int ntr = in_sizes[1] / KDIM;  // 4096
  int n = ns + ntr;              // 8192

  char* ws = (char*)d_ws;
  unsigned short* Tp = (unsigned short*)ws;  // 4 MiB packed bf16 matrix
  size_t off = (size_t)n * KDIM * sizeof(unsigned short);
  float* sq = (float*)(ws + off);    off += (size_t)n * 4;
  float* pscol = (float*)(ws + off); off += (size_t)SBLK * 256 * 4;
  float* psums = (float*)(ws + off); off += SBLK * 4;
  float* coef = (float*)(ws + off);

  float* out = (float*)d_out;
  int nb = n / BT;                 // 64
  int nTiles = nb * (nb + 1) / 2;  // 2080

  mmd_stage<<<SBLK, 256, 0, stream>>>(src, tgt, ns, Tp, sq, pscol, psums);
  mmd_prep2<<<1, 256, 0, stream>>>(pscol, psums, coef, out, n);
  mmd_main<<<PBLK, 256, 0, stream>>>(Tp, sq, coef, out, ns / BT,
                                     1.f / ((float)ns * (float)ns), nTiles);
}